// Round 4
// baseline (837.033 us; speedup 1.0000x reference)
//
#include <hip/hip_runtime.h>
#include <hip/hip_bf16.h>
#include <cstdint>
#include <cstddef>

#define NN 100000
#define EE 1600000
#define GG 2048

constexpr int NB_SCAN = (NN + 255) / 256; // 391 blocks over nodes

__device__ __forceinline__ float lrelu(float v) { return v > 0.f ? v : 0.2f * v; }

// ---------------- CSR build (dst -> list of src), reused by all 3 layers ----
__global__ void k_count(const int* __restrict__ ei, int* __restrict__ deg) {
    int i = blockIdx.x * blockDim.x + threadIdx.x;
    if (i >= EE + NN) return;
    int d = (i < EE) ? ei[EE + i] : (i - EE);
    atomicAdd(&deg[d], 1);
}

__global__ void k_scan1(const int* __restrict__ deg, int* __restrict__ offs,
                        int* __restrict__ bsums) {
    __shared__ int tmp[256];
    int tid = threadIdx.x;
    int i = blockIdx.x * 256 + tid;
    int v = (i < NN) ? deg[i] : 0;
    tmp[tid] = v; __syncthreads();
    for (int off = 1; off < 256; off <<= 1) {
        int t = (tid >= off) ? tmp[tid - off] : 0;
        __syncthreads();
        tmp[tid] += t;
        __syncthreads();
    }
    if (i < NN) offs[i] = tmp[tid] - v;   // exclusive within block
    if (tid == 255) bsums[blockIdx.x] = tmp[255];
}

__global__ void k_scan2(int* __restrict__ bsums) {
    __shared__ int tmp[512];
    int tid = threadIdx.x;
    int v = (tid < NB_SCAN) ? bsums[tid] : 0;
    tmp[tid] = v; __syncthreads();
    for (int off = 1; off < 512; off <<= 1) {
        int t = (tid >= off) ? tmp[tid - off] : 0;
        __syncthreads();
        tmp[tid] += t;
        __syncthreads();
    }
    if (tid < NB_SCAN) bsums[tid] = tmp[tid] - v;  // exclusive block offsets
}

__global__ void k_scan3(int* __restrict__ offs, const int* __restrict__ bsums) {
    int i = blockIdx.x * 256 + threadIdx.x;
    if (i < NN) offs[i] += bsums[blockIdx.x];
}

__global__ void k_scatter(const int* __restrict__ ei, const int* __restrict__ offs,
                          int* __restrict__ cursor, int* __restrict__ col) {
    int i = blockIdx.x * blockDim.x + threadIdx.x;
    if (i >= EE + NN) return;
    int s, d;
    if (i < EE) { s = ei[i]; d = ei[EE + i]; } else { s = d = i - EE; }
    int pos = offs[d] + atomicAdd(&cursor[d], 1);
    col[pos] = s;
}

// ---------------- GEMM + fused attention-logit epilogue ---------------------
// 16 rows per block, 4 rows per thread; one W load feeds 4 FMAs.
__global__ __launch_bounds__(256) void k_gemm(const float* __restrict__ X,
                                              const float* __restrict__ W,
                                              const float* __restrict__ asrc,
                                              const float* __restrict__ adst,
                                              float* __restrict__ H,
                                              float* __restrict__ als,
                                              float* __restrict__ ald, int fin) {
    __shared__ float xs[16 * 128];
    int j  = threadIdx.x & 63;   // output col; one wave handles 4 rows
    int ty = threadIdx.x >> 6;   // wave id 0..3
    int row0 = blockIdx.x * 16;
    int f4 = fin >> 2;                         // float4 per row (32 or 16)
    int lg = (fin == 128) ? 5 : 4;             // log2(f4)
    const float4* X4 = (const float4*)X;
    int tot4 = 16 * f4;
    for (int idx = threadIdx.x; idx < tot4; idx += 256) {
        int r = idx >> lg, k4 = idx & (f4 - 1);
        ((float4*)xs)[idx] = X4[(size_t)(row0 + r) * f4 + k4];
    }
    __syncthreads();
    const float* x0 = xs + (ty * 4 + 0) * fin;
    const float* x1 = xs + (ty * 4 + 1) * fin;
    const float* x2 = xs + (ty * 4 + 2) * fin;
    const float* x3 = xs + (ty * 4 + 3) * fin;
    float a0 = 0.f, a1 = 0.f, a2 = 0.f, a3 = 0.f;
    for (int k = 0; k < fin; k++) {
        float w = W[k * 64 + j];
        a0 += x0[k] * w; a1 += x1[k] * w; a2 += x2[k] * w; a3 += x3[k] * w;
    }
    int row = row0 + ty * 4;
    H[(size_t)(row + 0) * 64 + j] = a0;
    H[(size_t)(row + 1) * 64 + j] = a1;
    H[(size_t)(row + 2) * 64 + j] = a2;
    H[(size_t)(row + 3) * 64 + j] = a3;
    float asj = asrc[j], adj = adst[j];
    float accs[4] = {a0, a1, a2, a3};
#pragma unroll
    for (int r = 0; r < 4; r++) {
        float vs = accs[r] * asj;
        float vd = accs[r] * adj;
#pragma unroll
        for (int off = 8; off > 0; off >>= 1) {
            vs += __shfl_xor(vs, off, 64);
            vd += __shfl_xor(vd, off, 64);
        }
        if ((j & 15) == 0) {
            int h = j >> 4;
            als[(size_t)(row + r) * 4 + h] = vs;
            ald[(size_t)(row + r) * 4 + h] = vd;
        }
    }
}

// one wave per destination node: single-pass segment softmax + quad-gather
__global__ __launch_bounds__(256) void k_agg(
    const float* __restrict__ H, const float* __restrict__ als,
    const float* __restrict__ ald, const int* __restrict__ offs,
    const int* __restrict__ deg, const int* __restrict__ col,
    const float* __restrict__ bias, float* __restrict__ Hout,
    const int* __restrict__ batch, const float* __restrict__ hw,
    float* __restrict__ out, int last) {
    __shared__ float lws[4][64 * 4];  // per-wave: unnormalized weights [e][h]
    __shared__ int   lsi[4][64];      // per-wave: src index per edge
    int lane = threadIdx.x & 63;
    int wid  = threadIdx.x >> 6;
    int n = blockIdx.x * 4 + wid;
    if (n >= NN) return;
    int start = offs[n];
    int len = deg[n];
    float4 ad4 = ((const float4*)ald)[n];
    float adv[4] = {ad4.x, ad4.y, ad4.z, ad4.w};

    if (len <= 64) {
        // ---- softmax: lane e owns edge e ----
        float ev0 = -1e30f, ev1 = -1e30f, ev2 = -1e30f, ev3 = -1e30f;
        int s = 0;
        if (lane < len) {
            s = col[start + lane];
            float4 a = ((const float4*)als)[s];
            ev0 = lrelu(a.x + adv[0]); ev1 = lrelu(a.y + adv[1]);
            ev2 = lrelu(a.z + adv[2]); ev3 = lrelu(a.w + adv[3]);
        }
        float m0 = ev0, m1 = ev1, m2 = ev2, m3 = ev3;
#pragma unroll
        for (int off = 32; off > 0; off >>= 1) {
            m0 = fmaxf(m0, __shfl_xor(m0, off, 64));
            m1 = fmaxf(m1, __shfl_xor(m1, off, 64));
            m2 = fmaxf(m2, __shfl_xor(m2, off, 64));
            m3 = fmaxf(m3, __shfl_xor(m3, off, 64));
        }
        float w0 = 0.f, w1 = 0.f, w2 = 0.f, w3 = 0.f;
        if (lane < len) {
            w0 = __expf(ev0 - m0); w1 = __expf(ev1 - m1);
            w2 = __expf(ev2 - m2); w3 = __expf(ev3 - m3);
        }
        float s0 = w0, s1 = w1, s2 = w2, s3 = w3;
#pragma unroll
        for (int off = 32; off > 0; off >>= 1) {
            s0 += __shfl_xor(s0, off, 64); s1 += __shfl_xor(s1, off, 64);
            s2 += __shfl_xor(s2, off, 64); s3 += __shfl_xor(s3, off, 64);
        }
        if (lane < len) {
            ((float4*)&lws[wid][lane * 4])[0] = make_float4(w0, w1, w2, w3);
            lsi[wid][lane] = s;
        }
        // ---- quad-gather: lane = (edge-offset sub4, float4-channel c4) ----
        // one wave instr fetches 4 full rows (1 KB); 4-deep unroll = 16 edges,
        // 4 KB in flight per wave.
        int sub4 = lane >> 4;      // 0..3 edge offset within group
        int c4   = lane & 15;      // float4 index within row (channels 4c4..4c4+3)
        int hh4  = c4 >> 2;        // head of this channel quad
        float smh = hh4 == 0 ? s0 : hh4 == 1 ? s1 : hh4 == 2 ? s2 : s3;
        float inv = 1.f / (smh + 1e-16f);
        const float4* H4 = (const float4*)H;
        float4 acc0 = {0,0,0,0}, acc1 = {0,0,0,0}, acc2 = {0,0,0,0}, acc3 = {0,0,0,0};
        for (int e = 0; e < len; e += 16) {
            int i0 = e + 0  + sub4, i1 = e + 4  + sub4;
            int i2 = e + 8  + sub4, i3 = e + 12 + sub4;
            bool v0 = i0 < len, v1 = i1 < len, v2 = i2 < len, v3 = i3 < len;
            int c0 = v0 ? i0 : 0, c1i = v1 ? i1 : 0;
            int c2i = v2 ? i2 : 0, c3i = v3 ? i3 : 0;
            int sa = lsi[wid][c0],  sb = lsi[wid][c1i];
            int sc = lsi[wid][c2i], sd = lsi[wid][c3i];
            float wa = lws[wid][c0  * 4 + hh4]; wa = v0 ? wa : 0.f;
            float wb = lws[wid][c1i * 4 + hh4]; wb = v1 ? wb : 0.f;
            float wc = lws[wid][c2i * 4 + hh4]; wc = v2 ? wc : 0.f;
            float wd = lws[wid][c3i * 4 + hh4]; wd = v3 ? wd : 0.f;
            float4 ha = H4[(size_t)sa * 16 + c4];
            float4 hb = H4[(size_t)sb * 16 + c4];
            float4 hc = H4[(size_t)sc * 16 + c4];
            float4 hd = H4[(size_t)sd * 16 + c4];
            acc0.x += wa * ha.x; acc0.y += wa * ha.y; acc0.z += wa * ha.z; acc0.w += wa * ha.w;
            acc1.x += wb * hb.x; acc1.y += wb * hb.y; acc1.z += wb * hb.z; acc1.w += wb * hb.w;
            acc2.x += wc * hc.x; acc2.y += wc * hc.y; acc2.z += wc * hc.z; acc2.w += wc * hc.w;
            acc3.x += wd * hd.x; acc3.y += wd * hd.y; acc3.z += wd * hd.z; acc3.w += wd * hd.w;
        }
        float4 acc;
        acc.x = acc0.x + acc1.x + acc2.x + acc3.x;
        acc.y = acc0.y + acc1.y + acc2.y + acc3.y;
        acc.z = acc0.z + acc1.z + acc2.z + acc3.z;
        acc.w = acc0.w + acc1.w + acc2.w + acc3.w;
#pragma unroll
        for (int off = 16; off <= 32; off <<= 1) {   // combine 4 edge-offset groups
            acc.x += __shfl_xor(acc.x, off, 64);
            acc.y += __shfl_xor(acc.y, off, 64);
            acc.z += __shfl_xor(acc.z, off, 64);
            acc.w += __shfl_xor(acc.w, off, 64);
        }
        float4 b4 = ((const float4*)bias)[c4];
        float4 o4;
        o4.x = fmaxf(acc.x * inv + b4.x, 0.f);
        o4.y = fmaxf(acc.y * inv + b4.y, 0.f);
        o4.z = fmaxf(acc.z * inv + b4.z, 0.f);
        o4.w = fmaxf(acc.w * inv + b4.w, 0.f);
        if (!last) {
            if (sub4 == 0) ((float4*)(Hout + (size_t)n * 64))[c4] = o4;
        } else {
            float4 w4 = ((const float4*)hw)[c4];
            float t = (sub4 == 0)
                ? (o4.x * w4.x + o4.y * w4.y + o4.z * w4.z + o4.w * w4.w) : 0.f;
#pragma unroll
            for (int off = 32; off > 0; off >>= 1) t += __shfl_xor(t, off, 64);
            if (lane == 0) atomicAdd(&out[batch[n]], t);
        }
        return;
    }

    // rare fallback (len > 64): 3-phase path, lane = channel
    int hh = lane >> 4;
    float mx[4] = {-1e30f, -1e30f, -1e30f, -1e30f};
    for (int e = lane; e < len; e += 64) {
        int s = col[start + e];
        float4 a = ((const float4*)als)[s];
        mx[0] = fmaxf(mx[0], lrelu(a.x + adv[0]));
        mx[1] = fmaxf(mx[1], lrelu(a.y + adv[1]));
        mx[2] = fmaxf(mx[2], lrelu(a.z + adv[2]));
        mx[3] = fmaxf(mx[3], lrelu(a.w + adv[3]));
    }
#pragma unroll
    for (int off = 32; off > 0; off >>= 1)
#pragma unroll
        for (int h = 0; h < 4; h++) mx[h] = fmaxf(mx[h], __shfl_xor(mx[h], off, 64));
    float sm[4] = {0.f, 0.f, 0.f, 0.f};
    for (int e = lane; e < len; e += 64) {
        int s = col[start + e];
        float4 a = ((const float4*)als)[s];
        sm[0] += __expf(lrelu(a.x + adv[0]) - mx[0]);
        sm[1] += __expf(lrelu(a.y + adv[1]) - mx[1]);
        sm[2] += __expf(lrelu(a.z + adv[2]) - mx[2]);
        sm[3] += __expf(lrelu(a.w + adv[3]) - mx[3]);
    }
#pragma unroll
    for (int off = 32; off > 0; off >>= 1)
#pragma unroll
        for (int h = 0; h < 4; h++) sm[h] += __shfl_xor(sm[h], off, 64);
    float mh = mx[hh];
    float ih = 1.f / (sm[hh] + 1e-16f);
    float ah = adv[hh];
    float acc = 0.f;
    for (int e = 0; e < len; e++) {
        int s = col[start + e];
        float alpha = __expf(lrelu(als[(size_t)s * 4 + hh] + ah) - mh) * ih;
        acc += alpha * H[(size_t)s * 64 + lane];
    }
    float o = fmaxf(acc + bias[lane], 0.f);
    if (!last) {
        Hout[(size_t)n * 64 + lane] = o;
    } else {
        float t = o * hw[lane];
#pragma unroll
        for (int off = 32; off > 0; off >>= 1) t += __shfl_xor(t, off, 64);
        if (lane == 0) atomicAdd(&out[batch[n]], t);
    }
}

// ---------------- output init ------------------------------------------------
__global__ void k_out_init(const float* __restrict__ head_b, float* __restrict__ out) {
    int g = blockIdx.x * blockDim.x + threadIdx.x;
    if (g < GG) out[g] = head_b[0];
}

// ---------------- launch -----------------------------------------------------
extern "C" void kernel_launch(void* const* d_in, const int* in_sizes, int n_in,
                              void* d_out, int out_size, void* d_ws, size_t ws_size,
                              hipStream_t stream) {
    const float* x     = (const float*)d_in[0];
    const int*   ei    = (const int*)d_in[1];
    const int*   batch = (const int*)d_in[2];
    const float* Wm[3] = {(const float*)d_in[3], (const float*)d_in[7],  (const float*)d_in[11]};
    const float* As[3] = {(const float*)d_in[4], (const float*)d_in[8],  (const float*)d_in[12]};
    const float* Ad[3] = {(const float*)d_in[5], (const float*)d_in[9],  (const float*)d_in[13]};
    const float* Bb[3] = {(const float*)d_in[6], (const float*)d_in[10], (const float*)d_in[14]};
    const float* hw = (const float*)d_in[15];
    const float* hb = (const float*)d_in[16];
    float* out = (float*)d_out;

    uint8_t* w = (uint8_t*)d_ws;
    auto alloc = [&](size_t bytes) -> void* {
        void* p = (void*)w;
        w += (bytes + 255) & ~(size_t)255;
        return p;
    };
    float* A      = (float*)alloc((size_t)NN * 64 * 4);   // gemm output
    float* Bf     = (float*)alloc((size_t)NN * 64 * 4);   // aggregated output
    float* als    = (float*)alloc((size_t)NN * 4 * 4);
    float* ald    = (float*)alloc((size_t)NN * 4 * 4);
    int*   deg    = (int*)alloc((size_t)NN * 4);
    int*   offs   = (int*)alloc((size_t)NN * 4);
    int*   cursor = (int*)alloc((size_t)NN * 4);
    int*   col    = (int*)alloc((size_t)(EE + NN) * 4);
    int*   bsums  = (int*)alloc((size_t)((NB_SCAN + 63) & ~63) * 4);

    hipMemsetAsync(deg, 0, (size_t)NN * 4, stream);
    hipMemsetAsync(cursor, 0, (size_t)NN * 4, stream);

    int eb = (EE + NN + 255) / 256;
    k_count  <<<eb, 256, 0, stream>>>(ei, deg);
    k_scan1  <<<NB_SCAN, 256, 0, stream>>>(deg, offs, bsums);
    k_scan2  <<<1, 512, 0, stream>>>(bsums);
    k_scan3  <<<NB_SCAN, 256, 0, stream>>>(offs, bsums);
    k_scatter<<<eb, 256, 0, stream>>>(ei, offs, cursor, col);
    k_out_init<<<(GG + 255) / 256, 256, 0, stream>>>(hb, out);

    const float* cur_in = x;
    int fin = 128;
    for (int L = 0; L < 3; L++) {
        k_gemm<<<NN / 16, 256, 0, stream>>>(
            cur_in, Wm[L], As[L], Ad[L], A, als, ald, fin);
        k_agg <<<(NN + 3) / 4, 256, 0, stream>>>(
            A, als, ald, offs, deg, col, Bb[L], Bf, batch, hw, out, (L == 2) ? 1 : 0);
        cur_in = Bf;
        fin = 64;
    }
}

// Round 5
// 736.838 us; speedup vs baseline: 1.1360x; 1.1360x over previous
//
#include <hip/hip_runtime.h>
#include <hip/hip_bf16.h>
#include <hip/hip_fp16.h>
#include <cstdint>
#include <cstddef>

#define NN 100000
#define EE 1600000
#define GG 2048

constexpr int NB_SCAN = (NN + 255) / 256; // 391 blocks over nodes

typedef __attribute__((ext_vector_type(4))) _Float16 half4v;

__device__ __forceinline__ float lrelu(float v) { return v > 0.f ? v : 0.2f * v; }

// ---------------- CSR build (dst -> list of src), reused by all 3 layers ----
__global__ void k_count(const int* __restrict__ ei, int* __restrict__ deg) {
    int i = blockIdx.x * blockDim.x + threadIdx.x;
    if (i >= EE + NN) return;
    int d = (i < EE) ? ei[EE + i] : (i - EE);
    atomicAdd(&deg[d], 1);
}

__global__ void k_scan1(const int* __restrict__ deg, int* __restrict__ offs,
                        int* __restrict__ bsums) {
    __shared__ int tmp[256];
    int tid = threadIdx.x;
    int i = blockIdx.x * 256 + tid;
    int v = (i < NN) ? deg[i] : 0;
    tmp[tid] = v; __syncthreads();
    for (int off = 1; off < 256; off <<= 1) {
        int t = (tid >= off) ? tmp[tid - off] : 0;
        __syncthreads();
        tmp[tid] += t;
        __syncthreads();
    }
    if (i < NN) offs[i] = tmp[tid] - v;   // exclusive within block
    if (tid == 255) bsums[blockIdx.x] = tmp[255];
}

__global__ void k_scan2(int* __restrict__ bsums) {
    __shared__ int tmp[512];
    int tid = threadIdx.x;
    int v = (tid < NB_SCAN) ? bsums[tid] : 0;
    tmp[tid] = v; __syncthreads();
    for (int off = 1; off < 512; off <<= 1) {
        int t = (tid >= off) ? tmp[tid - off] : 0;
        __syncthreads();
        tmp[tid] += t;
        __syncthreads();
    }
    if (tid < NB_SCAN) bsums[tid] = tmp[tid] - v;  // exclusive block offsets
}

__global__ void k_scan3(int* __restrict__ offs, const int* __restrict__ bsums) {
    int i = blockIdx.x * 256 + threadIdx.x;
    if (i < NN) offs[i] += bsums[blockIdx.x];
}

__global__ void k_scatter(const int* __restrict__ ei, const int* __restrict__ offs,
                          int* __restrict__ cursor, int* __restrict__ col) {
    int i = blockIdx.x * blockDim.x + threadIdx.x;
    if (i >= EE + NN) return;
    int s, d;
    if (i < EE) { s = ei[i]; d = ei[EE + i]; } else { s = d = i - EE; }
    int pos = offs[d] + atomicAdd(&cursor[d], 1);
    col[pos] = s;
}

// ---------------- GEMM + fused attention-logit epilogue ---------------------
// 16 rows per block, 4 rows per thread; one W load feeds 4 FMAs.
// Logits (als/ald) computed in fp32 from the exact accumulator; feature rows
// stored as fp16 ONLY for the k_agg message gather (halves fabric traffic).
__global__ __launch_bounds__(256) void k_gemm(const float* __restrict__ X,
                                              const float* __restrict__ W,
                                              const float* __restrict__ asrc,
                                              const float* __restrict__ adst,
                                              _Float16* __restrict__ Hh,
                                              float* __restrict__ als,
                                              float* __restrict__ ald, int fin) {
    __shared__ float xs[16 * 128];
    int j  = threadIdx.x & 63;   // output col; one wave handles 4 rows
    int ty = threadIdx.x >> 6;   // wave id 0..3
    int row0 = blockIdx.x * 16;
    int f4 = fin >> 2;                         // float4 per row (32 or 16)
    int lg = (fin == 128) ? 5 : 4;             // log2(f4)
    const float4* X4 = (const float4*)X;
    int tot4 = 16 * f4;
    for (int idx = threadIdx.x; idx < tot4; idx += 256) {
        int r = idx >> lg, k4 = idx & (f4 - 1);
        ((float4*)xs)[idx] = X4[(size_t)(row0 + r) * f4 + k4];
    }
    __syncthreads();
    const float* x0 = xs + (ty * 4 + 0) * fin;
    const float* x1 = xs + (ty * 4 + 1) * fin;
    const float* x2 = xs + (ty * 4 + 2) * fin;
    const float* x3 = xs + (ty * 4 + 3) * fin;
    float a0 = 0.f, a1 = 0.f, a2 = 0.f, a3 = 0.f;
    for (int k = 0; k < fin; k++) {
        float w = W[k * 64 + j];
        a0 += x0[k] * w; a1 += x1[k] * w; a2 += x2[k] * w; a3 += x3[k] * w;
    }
    int row = row0 + ty * 4;
    Hh[(size_t)(row + 0) * 64 + j] = (_Float16)a0;
    Hh[(size_t)(row + 1) * 64 + j] = (_Float16)a1;
    Hh[(size_t)(row + 2) * 64 + j] = (_Float16)a2;
    Hh[(size_t)(row + 3) * 64 + j] = (_Float16)a3;
    float asj = asrc[j], adj = adst[j];
    float accs[4] = {a0, a1, a2, a3};
#pragma unroll
    for (int r = 0; r < 4; r++) {
        float vs = accs[r] * asj;
        float vd = accs[r] * adj;
#pragma unroll
        for (int off = 8; off > 0; off >>= 1) {
            vs += __shfl_xor(vs, off, 64);
            vd += __shfl_xor(vd, off, 64);
        }
        if ((j & 15) == 0) {
            int h = j >> 4;
            als[(size_t)(row + r) * 4 + h] = vs;
            ald[(size_t)(row + r) * 4 + h] = vd;
        }
    }
}

// one wave per destination node: single-pass segment softmax + fp16 quad-gather
__global__ __launch_bounds__(256) void k_agg(
    const _Float16* __restrict__ Hh, const float* __restrict__ als,
    const float* __restrict__ ald, const int* __restrict__ offs,
    const int* __restrict__ deg, const int* __restrict__ col,
    const float* __restrict__ bias, float* __restrict__ Hout,
    const int* __restrict__ batch, const float* __restrict__ hw,
    float* __restrict__ out, int last) {
    __shared__ float lws[4][64 * 4];  // per-wave: unnormalized weights [e][h]
    __shared__ int   lsi[4][64];      // per-wave: src index per edge
    int lane = threadIdx.x & 63;
    int wid  = threadIdx.x >> 6;
    int n = blockIdx.x * 4 + wid;
    if (n >= NN) return;
    int start = offs[n];
    int len = deg[n];
    float4 ad4 = ((const float4*)ald)[n];
    float adv[4] = {ad4.x, ad4.y, ad4.z, ad4.w};

    if (len <= 64) {
        // ---- softmax: lane e owns edge e ----
        float ev0 = -1e30f, ev1 = -1e30f, ev2 = -1e30f, ev3 = -1e30f;
        int s = 0;
        if (lane < len) {
            s = col[start + lane];
            float4 a = ((const float4*)als)[s];
            ev0 = lrelu(a.x + adv[0]); ev1 = lrelu(a.y + adv[1]);
            ev2 = lrelu(a.z + adv[2]); ev3 = lrelu(a.w + adv[3]);
        }
        float m0 = ev0, m1 = ev1, m2 = ev2, m3 = ev3;
#pragma unroll
        for (int off = 32; off > 0; off >>= 1) {
            m0 = fmaxf(m0, __shfl_xor(m0, off, 64));
            m1 = fmaxf(m1, __shfl_xor(m1, off, 64));
            m2 = fmaxf(m2, __shfl_xor(m2, off, 64));
            m3 = fmaxf(m3, __shfl_xor(m3, off, 64));
        }
        float w0 = 0.f, w1 = 0.f, w2 = 0.f, w3 = 0.f;
        if (lane < len) {
            w0 = __expf(ev0 - m0); w1 = __expf(ev1 - m1);
            w2 = __expf(ev2 - m2); w3 = __expf(ev3 - m3);
        }
        float s0 = w0, s1 = w1, s2 = w2, s3 = w3;
#pragma unroll
        for (int off = 32; off > 0; off >>= 1) {
            s0 += __shfl_xor(s0, off, 64); s1 += __shfl_xor(s1, off, 64);
            s2 += __shfl_xor(s2, off, 64); s3 += __shfl_xor(s3, off, 64);
        }
        if (lane < len) {
            ((float4*)&lws[wid][lane * 4])[0] = make_float4(w0, w1, w2, w3);
            lsi[wid][lane] = s;
        }
        // ---- fp16 quad-gather: lane = (edge-offset sub4, half4-channel c4) ----
        // 16 lanes x 8 B = one 128 B row; 4 rows per instr; unroll = 16 edges.
        int sub4 = lane >> 4;      // 0..3 edge offset within group
        int c4   = lane & 15;      // half4 index within row (channels 4c4..4c4+3)
        int hh4  = c4 >> 2;        // head of this channel quad
        float smh = hh4 == 0 ? s0 : hh4 == 1 ? s1 : hh4 == 2 ? s2 : s3;
        float inv = 1.f / (smh + 1e-16f);
        const half4v* H4 = (const half4v*)Hh;
        float4 acc0 = {0,0,0,0}, acc1 = {0,0,0,0}, acc2 = {0,0,0,0}, acc3 = {0,0,0,0};
        for (int e = 0; e < len; e += 16) {
            int i0 = e + 0  + sub4, i1 = e + 4  + sub4;
            int i2 = e + 8  + sub4, i3 = e + 12 + sub4;
            bool v0 = i0 < len, v1 = i1 < len, v2 = i2 < len, v3 = i3 < len;
            int c0 = v0 ? i0 : 0, c1i = v1 ? i1 : 0;
            int c2i = v2 ? i2 : 0, c3i = v3 ? i3 : 0;
            int sa = lsi[wid][c0],  sb = lsi[wid][c1i];
            int sc = lsi[wid][c2i], sd = lsi[wid][c3i];
            float wa = lws[wid][c0  * 4 + hh4]; wa = v0 ? wa : 0.f;
            float wb = lws[wid][c1i * 4 + hh4]; wb = v1 ? wb : 0.f;
            float wc = lws[wid][c2i * 4 + hh4]; wc = v2 ? wc : 0.f;
            float wd = lws[wid][c3i * 4 + hh4]; wd = v3 ? wd : 0.f;
            half4v ha = H4[(size_t)sa * 16 + c4];
            half4v hb = H4[(size_t)sb * 16 + c4];
            half4v hc = H4[(size_t)sc * 16 + c4];
            half4v hd = H4[(size_t)sd * 16 + c4];
            acc0.x += wa * (float)ha.x; acc0.y += wa * (float)ha.y;
            acc0.z += wa * (float)ha.z; acc0.w += wa * (float)ha.w;
            acc1.x += wb * (float)hb.x; acc1.y += wb * (float)hb.y;
            acc1.z += wb * (float)hb.z; acc1.w += wb * (float)hb.w;
            acc2.x += wc * (float)hc.x; acc2.y += wc * (float)hc.y;
            acc2.z += wc * (float)hc.z; acc2.w += wc * (float)hc.w;
            acc3.x += wd * (float)hd.x; acc3.y += wd * (float)hd.y;
            acc3.z += wd * (float)hd.z; acc3.w += wd * (float)hd.w;
        }
        float4 acc;
        acc.x = acc0.x + acc1.x + acc2.x + acc3.x;
        acc.y = acc0.y + acc1.y + acc2.y + acc3.y;
        acc.z = acc0.z + acc1.z + acc2.z + acc3.z;
        acc.w = acc0.w + acc1.w + acc2.w + acc3.w;
#pragma unroll
        for (int off = 16; off <= 32; off <<= 1) {   // combine 4 edge-offset groups
            acc.x += __shfl_xor(acc.x, off, 64);
            acc.y += __shfl_xor(acc.y, off, 64);
            acc.z += __shfl_xor(acc.z, off, 64);
            acc.w += __shfl_xor(acc.w, off, 64);
        }
        float4 b4 = ((const float4*)bias)[c4];
        float4 o4;
        o4.x = fmaxf(acc.x * inv + b4.x, 0.f);
        o4.y = fmaxf(acc.y * inv + b4.y, 0.f);
        o4.z = fmaxf(acc.z * inv + b4.z, 0.f);
        o4.w = fmaxf(acc.w * inv + b4.w, 0.f);
        if (!last) {
            if (sub4 == 0) ((float4*)(Hout + (size_t)n * 64))[c4] = o4;
        } else {
            float4 w4 = ((const float4*)hw)[c4];
            float t = (sub4 == 0)
                ? (o4.x * w4.x + o4.y * w4.y + o4.z * w4.z + o4.w * w4.w) : 0.f;
#pragma unroll
            for (int off = 32; off > 0; off >>= 1) t += __shfl_xor(t, off, 64);
            if (lane == 0) atomicAdd(&out[batch[n]], t);
        }
        return;
    }

    // rare fallback (len > 64): 3-phase path, lane = channel
    int hh = lane >> 4;
    float mx[4] = {-1e30f, -1e30f, -1e30f, -1e30f};
    for (int e = lane; e < len; e += 64) {
        int s = col[start + e];
        float4 a = ((const float4*)als)[s];
        mx[0] = fmaxf(mx[0], lrelu(a.x + adv[0]));
        mx[1] = fmaxf(mx[1], lrelu(a.y + adv[1]));
        mx[2] = fmaxf(mx[2], lrelu(a.z + adv[2]));
        mx[3] = fmaxf(mx[3], lrelu(a.w + adv[3]));
    }
#pragma unroll
    for (int off = 32; off > 0; off >>= 1)
#pragma unroll
        for (int h = 0; h < 4; h++) mx[h] = fmaxf(mx[h], __shfl_xor(mx[h], off, 64));
    float sm[4] = {0.f, 0.f, 0.f, 0.f};
    for (int e = lane; e < len; e += 64) {
        int s = col[start + e];
        float4 a = ((const float4*)als)[s];
        sm[0] += __expf(lrelu(a.x + adv[0]) - mx[0]);
        sm[1] += __expf(lrelu(a.y + adv[1]) - mx[1]);
        sm[2] += __expf(lrelu(a.z + adv[2]) - mx[2]);
        sm[3] += __expf(lrelu(a.w + adv[3]) - mx[3]);
    }
#pragma unroll
    for (int off = 32; off > 0; off >>= 1)
#pragma unroll
        for (int h = 0; h < 4; h++) sm[h] += __shfl_xor(sm[h], off, 64);
    float mh = mx[hh];
    float ih = 1.f / (sm[hh] + 1e-16f);
    float ah = adv[hh];
    float acc = 0.f;
    for (int e = 0; e < len; e++) {
        int s = col[start + e];
        float alpha = __expf(lrelu(als[(size_t)s * 4 + hh] + ah) - mh) * ih;
        acc += alpha * (float)Hh[(size_t)s * 64 + lane];
    }
    float o = fmaxf(acc + bias[lane], 0.f);
    if (!last) {
        Hout[(size_t)n * 64 + lane] = o;
    } else {
        float t = o * hw[lane];
#pragma unroll
        for (int off = 32; off > 0; off >>= 1) t += __shfl_xor(t, off, 64);
        if (lane == 0) atomicAdd(&out[batch[n]], t);
    }
}

// ---------------- output init ------------------------------------------------
__global__ void k_out_init(const float* __restrict__ head_b, float* __restrict__ out) {
    int g = blockIdx.x * blockDim.x + threadIdx.x;
    if (g < GG) out[g] = head_b[0];
}

// ---------------- launch -----------------------------------------------------
extern "C" void kernel_launch(void* const* d_in, const int* in_sizes, int n_in,
                              void* d_out, int out_size, void* d_ws, size_t ws_size,
                              hipStream_t stream) {
    const float* x     = (const float*)d_in[0];
    const int*   ei    = (const int*)d_in[1];
    const int*   batch = (const int*)d_in[2];
    const float* Wm[3] = {(const float*)d_in[3], (const float*)d_in[7],  (const float*)d_in[11]};
    const float* As[3] = {(const float*)d_in[4], (const float*)d_in[8],  (const float*)d_in[12]};
    const float* Ad[3] = {(const float*)d_in[5], (const float*)d_in[9],  (const float*)d_in[13]};
    const float* Bb[3] = {(const float*)d_in[6], (const float*)d_in[10], (const float*)d_in[14]};
    const float* hw = (const float*)d_in[15];
    const float* hb = (const float*)d_in[16];
    float* out = (float*)d_out;

    uint8_t* w = (uint8_t*)d_ws;
    auto alloc = [&](size_t bytes) -> void* {
        void* p = (void*)w;
        w += (bytes + 255) & ~(size_t)255;
        return p;
    };
    _Float16* Hh   = (_Float16*)alloc((size_t)NN * 64 * 2);  // fp16 gather rows
    float* Bf      = (float*)alloc((size_t)NN * 64 * 4);     // aggregated output
    float* als     = (float*)alloc((size_t)NN * 4 * 4);
    float* ald     = (float*)alloc((size_t)NN * 4 * 4);
    int*   deg     = (int*)alloc((size_t)NN * 4);
    int*   offs    = (int*)alloc((size_t)NN * 4);
    int*   cursor  = (int*)alloc((size_t)NN * 4);
    int*   col     = (int*)alloc((size_t)(EE + NN) * 4);
    int*   bsums   = (int*)alloc((size_t)((NB_SCAN + 63) & ~63) * 4);

    hipMemsetAsync(deg, 0, (size_t)NN * 4, stream);
    hipMemsetAsync(cursor, 0, (size_t)NN * 4, stream);

    int eb = (EE + NN + 255) / 256;
    k_count  <<<eb, 256, 0, stream>>>(ei, deg);
    k_scan1  <<<NB_SCAN, 256, 0, stream>>>(deg, offs, bsums);
    k_scan2  <<<1, 512, 0, stream>>>(bsums);
    k_scan3  <<<NB_SCAN, 256, 0, stream>>>(offs, bsums);
    k_scatter<<<eb, 256, 0, stream>>>(ei, offs, cursor, col);
    k_out_init<<<(GG + 255) / 256, 256, 0, stream>>>(hb, out);

    const float* cur_in = x;
    int fin = 128;
    for (int L = 0; L < 3; L++) {
        k_gemm<<<NN / 16, 256, 0, stream>>>(
            cur_in, Wm[L], As[L], Ad[L], Hh, als, ald, fin);
        k_agg <<<(NN + 3) / 4, 256, 0, stream>>>(
            Hh, als, ald, offs, deg, col, Bb[L], Bf, batch, hw, out, (L == 2) ? 1 : 0);
        cur_in = Bf;
        fin = 64;
    }
}

// Round 7
// 648.048 us; speedup vs baseline: 1.2916x; 1.1370x over previous
//
#include <hip/hip_runtime.h>
#include <hip/hip_bf16.h>
#include <hip/hip_fp16.h>
#include <cstdint>
#include <cstddef>

#define NN 100000
#define EE 1600000
#define GG 2048

constexpr int NB_SCAN = (NN + 255) / 256; // 391 blocks over nodes

typedef __attribute__((ext_vector_type(4))) _Float16 half4v;

__device__ __forceinline__ float lrelu(float v) { return v > 0.f ? v : 0.2f * v; }

// ---------------- CSR build (dst -> list of src), reused by all 3 layers ----
__global__ void k_count(const int* __restrict__ ei, int* __restrict__ deg) {
    int i = blockIdx.x * blockDim.x + threadIdx.x;
    if (i >= EE + NN) return;
    int d = (i < EE) ? ei[EE + i] : (i - EE);
    atomicAdd(&deg[d], 1);
}

__global__ void k_scan1(const int* __restrict__ deg, int* __restrict__ offs,
                        int* __restrict__ bsums) {
    __shared__ int tmp[256];
    int tid = threadIdx.x;
    int i = blockIdx.x * 256 + tid;
    int v = (i < NN) ? deg[i] : 0;
    tmp[tid] = v; __syncthreads();
    for (int off = 1; off < 256; off <<= 1) {
        int t = (tid >= off) ? tmp[tid - off] : 0;
        __syncthreads();
        tmp[tid] += t;
        __syncthreads();
    }
    if (i < NN) offs[i] = tmp[tid] - v;   // exclusive within block
    if (tid == 255) bsums[blockIdx.x] = tmp[255];
}

__global__ void k_scan2(int* __restrict__ bsums) {
    __shared__ int tmp[512];
    int tid = threadIdx.x;
    int v = (tid < NB_SCAN) ? bsums[tid] : 0;
    tmp[tid] = v; __syncthreads();
    for (int off = 1; off < 512; off <<= 1) {
        int t = (tid >= off) ? tmp[tid - off] : 0;
        __syncthreads();
        tmp[tid] += t;
        __syncthreads();
    }
    if (tid < NB_SCAN) bsums[tid] = tmp[tid] - v;  // exclusive block offsets
}

__global__ void k_scan3(int* __restrict__ offs, const int* __restrict__ bsums) {
    int i = blockIdx.x * 256 + threadIdx.x;
    if (i < NN) offs[i] += bsums[blockIdx.x];
}

__global__ void k_scatter(const int* __restrict__ ei, const int* __restrict__ offs,
                          int* __restrict__ cursor, int* __restrict__ col) {
    int i = blockIdx.x * blockDim.x + threadIdx.x;
    if (i >= EE + NN) return;
    int s, d;
    if (i < EE) { s = ei[i]; d = ei[EE + i]; } else { s = d = i - EE; }
    int pos = offs[d] + atomicAdd(&cursor[d], 1);
    col[pos] = s;
}

// ---------------- GEMM + fused attention-logit epilogue ---------------------
__global__ __launch_bounds__(256) void k_gemm(const float* __restrict__ X,
                                              const float* __restrict__ W,
                                              const float* __restrict__ asrc,
                                              const float* __restrict__ adst,
                                              _Float16* __restrict__ Hh,
                                              float* __restrict__ als,
                                              float* __restrict__ ald, int fin) {
    __shared__ float xs[16 * 128];
    int j  = threadIdx.x & 63;   // output col; one wave handles 4 rows
    int ty = threadIdx.x >> 6;   // wave id 0..3
    int row0 = blockIdx.x * 16;
    int f4 = fin >> 2;                         // float4 per row (32 or 16)
    int lg = (fin == 128) ? 5 : 4;             // log2(f4)
    const float4* X4 = (const float4*)X;
    int tot4 = 16 * f4;
    for (int idx = threadIdx.x; idx < tot4; idx += 256) {
        int r = idx >> lg, k4 = idx & (f4 - 1);
        ((float4*)xs)[idx] = X4[(size_t)(row0 + r) * f4 + k4];
    }
    __syncthreads();
    const float* x0 = xs + (ty * 4 + 0) * fin;
    const float* x1 = xs + (ty * 4 + 1) * fin;
    const float* x2 = xs + (ty * 4 + 2) * fin;
    const float* x3 = xs + (ty * 4 + 3) * fin;
    float a0 = 0.f, a1 = 0.f, a2 = 0.f, a3 = 0.f;
    for (int k = 0; k < fin; k++) {
        float w = W[k * 64 + j];
        a0 += x0[k] * w; a1 += x1[k] * w; a2 += x2[k] * w; a3 += x3[k] * w;
    }
    int row = row0 + ty * 4;
    Hh[(size_t)(row + 0) * 64 + j] = (_Float16)a0;
    Hh[(size_t)(row + 1) * 64 + j] = (_Float16)a1;
    Hh[(size_t)(row + 2) * 64 + j] = (_Float16)a2;
    Hh[(size_t)(row + 3) * 64 + j] = (_Float16)a3;
    float asj = asrc[j], adj = adst[j];
    float accs[4] = {a0, a1, a2, a3};
#pragma unroll
    for (int r = 0; r < 4; r++) {
        float vs = accs[r] * asj;
        float vd = accs[r] * adj;
#pragma unroll
        for (int off = 8; off > 0; off >>= 1) {
            vs += __shfl_xor(vs, off, 64);
            vd += __shfl_xor(vd, off, 64);
        }
        if ((j & 15) == 0) {
            int h = j >> 4;
            als[(size_t)(row + r) * 4 + h] = vs;
            ald[(size_t)(row + r) * 4 + h] = vd;
        }
    }
}

// 16 lanes per node: softmax over edges + fp16 row gather, no cross-lane combine.
// Block = 256 threads = 16 nodes. Staging is written UNCONDITIONALLY (zeros for
// e >= len) and handed off through a block-uniform __syncthreads() — no reliance
// on wave-lockstep LDS visibility, no possibility of reading poisoned slots.
#define LWPITCH 260   // 64*4 + 4 pad words
__global__ __launch_bounds__(256) void k_agg(
    const _Float16* __restrict__ Hh, const float* __restrict__ als,
    const float* __restrict__ ald, const int* __restrict__ offs,
    const int* __restrict__ deg, const int* __restrict__ col,
    const float* __restrict__ bias, float* __restrict__ Hout,
    const int* __restrict__ batch, const float* __restrict__ hw,
    float* __restrict__ out, int last) {
    __shared__ float lws[16 * LWPITCH];  // [group][edge*4 + head]
    __shared__ int   lsi[16][64];        // [group][edge] = src index
    int tid = threadIdx.x;
    int g = tid >> 4;          // group (node) 0..15
    int l = tid & 15;          // lane in group = half4-chunk index 0..15
    int n = blockIdx.x * 16 + g;   // NN % 16 == 0 -> always valid
    int start = offs[n];
    int len = deg[n];
    float4 ad4 = ((const float4*)ald)[n];
    int hsel = l >> 2;         // head of this lane's channel quad
    const half4v* Hp = (const half4v*)Hh + l;
    float* lw = lws + g * LWPITCH;
    bool fast = (len <= 64);
    float inv = 1.f;

    if (fast) {
        // ---- stage: lane e (of 16) owns edges e, e+16, e+32, e+48 ----
        float ev[4][4];
        int   si[4];
        bool  vld[4];
        float m0 = -1e30f, m1 = -1e30f, m2 = -1e30f, m3 = -1e30f;
#pragma unroll
        for (int it = 0; it < 4; it++) {
            int e = l + it * 16;
            vld[it] = (e < len);
            int s = vld[it] ? col[start + e] : 0;
            si[it] = s;
            float4 a = ((const float4*)als)[s];
            ev[it][0] = lrelu(a.x + ad4.x); ev[it][1] = lrelu(a.y + ad4.y);
            ev[it][2] = lrelu(a.z + ad4.z); ev[it][3] = lrelu(a.w + ad4.w);
            if (vld[it]) {
                m0 = fmaxf(m0, ev[it][0]); m1 = fmaxf(m1, ev[it][1]);
                m2 = fmaxf(m2, ev[it][2]); m3 = fmaxf(m3, ev[it][3]);
            }
        }
#pragma unroll
        for (int off = 8; off > 0; off >>= 1) {
            m0 = fmaxf(m0, __shfl_xor(m0, off, 16));
            m1 = fmaxf(m1, __shfl_xor(m1, off, 16));
            m2 = fmaxf(m2, __shfl_xor(m2, off, 16));
            m3 = fmaxf(m3, __shfl_xor(m3, off, 16));
        }
        float s0 = 0.f, s1 = 0.f, s2 = 0.f, s3 = 0.f;
#pragma unroll
        for (int it = 0; it < 4; it++) {
            int e = l + it * 16;
            float w0 = vld[it] ? __expf(ev[it][0] - m0) : 0.f;
            float w1 = vld[it] ? __expf(ev[it][1] - m1) : 0.f;
            float w2 = vld[it] ? __expf(ev[it][2] - m2) : 0.f;
            float w3 = vld[it] ? __expf(ev[it][3] - m3) : 0.f;
            s0 += w0; s1 += w1; s2 += w2; s3 += w3;
            ((float4*)(lw + e * 4))[0] = make_float4(w0, w1, w2, w3);  // unconditional
            lsi[g][e] = vld[it] ? si[it] : 0;                          // unconditional
        }
#pragma unroll
        for (int off = 8; off > 0; off >>= 1) {
            s0 += __shfl_xor(s0, off, 16); s1 += __shfl_xor(s1, off, 16);
            s2 += __shfl_xor(s2, off, 16); s3 += __shfl_xor(s3, off, 16);
        }
        float smh = hsel == 0 ? s0 : hsel == 1 ? s1 : hsel == 2 ? s2 : s3;
        inv = 1.f / (smh + 1e-16f);
    }

    __syncthreads();   // block-uniform handoff: staging -> gather

    float4 acc = {0.f, 0.f, 0.f, 0.f};
    if (fast) {
        // ---- gather: lane l fetches chunk l of each src row ----
        int e = 0;
        for (; e + 4 <= len; e += 4) {   // 4 independent rows in flight per group
            int sa = lsi[g][e], sb = lsi[g][e + 1], sc = lsi[g][e + 2], sd = lsi[g][e + 3];
            float wa = lw[(e + 0) * 4 + hsel];
            float wb = lw[(e + 1) * 4 + hsel];
            float wc = lw[(e + 2) * 4 + hsel];
            float wd = lw[(e + 3) * 4 + hsel];
            half4v ha = Hp[(size_t)sa * 16];
            half4v hb = Hp[(size_t)sb * 16];
            half4v hc = Hp[(size_t)sc * 16];
            half4v hd = Hp[(size_t)sd * 16];
            acc.x += wa * (float)ha.x + wb * (float)hb.x + wc * (float)hc.x + wd * (float)hd.x;
            acc.y += wa * (float)ha.y + wb * (float)hb.y + wc * (float)hc.y + wd * (float)hd.y;
            acc.z += wa * (float)ha.z + wb * (float)hb.z + wc * (float)hc.z + wd * (float)hd.z;
            acc.w += wa * (float)ha.w + wb * (float)hb.w + wc * (float)hc.w + wd * (float)hd.w;
        }
        for (; e < len; e++) {
            int sa = lsi[g][e];
            float wa = lw[e * 4 + hsel];
            half4v ha = Hp[(size_t)sa * 16];
            acc.x += wa * (float)ha.x; acc.y += wa * (float)ha.y;
            acc.z += wa * (float)ha.z; acc.w += wa * (float)ha.w;
        }
    } else {
        // vanishingly-rare fallback (deg > 64): 3-phase recompute, no LDS
        float m0 = -1e30f, m1 = -1e30f, m2 = -1e30f, m3 = -1e30f;
        for (int e = l; e < len; e += 16) {
            int s = col[start + e];
            float4 a = ((const float4*)als)[s];
            m0 = fmaxf(m0, lrelu(a.x + ad4.x)); m1 = fmaxf(m1, lrelu(a.y + ad4.y));
            m2 = fmaxf(m2, lrelu(a.z + ad4.z)); m3 = fmaxf(m3, lrelu(a.w + ad4.w));
        }
#pragma unroll
        for (int off = 8; off > 0; off >>= 1) {
            m0 = fmaxf(m0, __shfl_xor(m0, off, 16));
            m1 = fmaxf(m1, __shfl_xor(m1, off, 16));
            m2 = fmaxf(m2, __shfl_xor(m2, off, 16));
            m3 = fmaxf(m3, __shfl_xor(m3, off, 16));
        }
        float s0 = 0.f, s1 = 0.f, s2 = 0.f, s3 = 0.f;
        for (int e = l; e < len; e += 16) {
            int s = col[start + e];
            float4 a = ((const float4*)als)[s];
            s0 += __expf(lrelu(a.x + ad4.x) - m0); s1 += __expf(lrelu(a.y + ad4.y) - m1);
            s2 += __expf(lrelu(a.z + ad4.z) - m2); s3 += __expf(lrelu(a.w + ad4.w) - m3);
        }
#pragma unroll
        for (int off = 8; off > 0; off >>= 1) {
            s0 += __shfl_xor(s0, off, 16); s1 += __shfl_xor(s1, off, 16);
            s2 += __shfl_xor(s2, off, 16); s3 += __shfl_xor(s3, off, 16);
        }
        float mh = hsel == 0 ? m0 : hsel == 1 ? m1 : hsel == 2 ? m2 : m3;
        float sh = hsel == 0 ? s0 : hsel == 1 ? s1 : hsel == 2 ? s2 : s3;
        float ih = 1.f / (sh + 1e-16f);
        float ah = hsel == 0 ? ad4.x : hsel == 1 ? ad4.y : hsel == 2 ? ad4.z : ad4.w;
        for (int e = 0; e < len; e++) {
            int s = col[start + e];
            float alpha = __expf(lrelu(als[(size_t)s * 4 + hsel] + ah) - mh) * ih;
            half4v ha = Hp[(size_t)s * 16];
            acc.x += alpha * (float)ha.x; acc.y += alpha * (float)ha.y;
            acc.z += alpha * (float)ha.z; acc.w += alpha * (float)ha.w;
        }
        inv = 1.f;
    }

    float4 b4 = ((const float4*)bias)[l];
    float4 o4;
    o4.x = fmaxf(acc.x * inv + b4.x, 0.f);
    o4.y = fmaxf(acc.y * inv + b4.y, 0.f);
    o4.z = fmaxf(acc.z * inv + b4.z, 0.f);
    o4.w = fmaxf(acc.w * inv + b4.w, 0.f);
    if (!last) {
        ((float4*)Hout)[(size_t)n * 16 + l] = o4;
    } else {
        float4 w4 = ((const float4*)hw)[l];
        float t = o4.x * w4.x + o4.y * w4.y + o4.z * w4.z + o4.w * w4.w;
#pragma unroll
        for (int off = 8; off > 0; off >>= 1) t += __shfl_xor(t, off, 16);
        if (l == 0) atomicAdd(&out[batch[n]], t);
    }
}

// ---------------- output init ------------------------------------------------
__global__ void k_out_init(const float* __restrict__ head_b, float* __restrict__ out) {
    int g = blockIdx.x * blockDim.x + threadIdx.x;
    if (g < GG) out[g] = head_b[0];
}

// ---------------- launch -----------------------------------------------------
extern "C" void kernel_launch(void* const* d_in, const int* in_sizes, int n_in,
                              void* d_out, int out_size, void* d_ws, size_t ws_size,
                              hipStream_t stream) {
    const float* x     = (const float*)d_in[0];
    const int*   ei    = (const int*)d_in[1];
    const int*   batch = (const int*)d_in[2];
    const float* Wm[3] = {(const float*)d_in[3], (const float*)d_in[7],  (const float*)d_in[11]};
    const float* As[3] = {(const float*)d_in[4], (const float*)d_in[8],  (const float*)d_in[12]};
    const float* Ad[3] = {(const float*)d_in[5], (const float*)d_in[9],  (const float*)d_in[13]};
    const float* Bb[3] = {(const float*)d_in[6], (const float*)d_in[10], (const float*)d_in[14]};
    const float* hw = (const float*)d_in[15];
    const float* hb = (const float*)d_in[16];
    float* out = (float*)d_out;

    uint8_t* w = (uint8_t*)d_ws;
    auto alloc = [&](size_t bytes) -> void* {
        void* p = (void*)w;
        w += (bytes + 255) & ~(size_t)255;
        return p;
    };
    _Float16* Hh   = (_Float16*)alloc((size_t)NN * 64 * 2);  // fp16 gather rows
    float* Bf      = (float*)alloc((size_t)NN * 64 * 4);     // aggregated output
    float* als     = (float*)alloc((size_t)NN * 4 * 4);
    float* ald     = (float*)alloc((size_t)NN * 4 * 4);
    int*   deg     = (int*)alloc((size_t)NN * 4);
    int*   offs    = (int*)alloc((size_t)NN * 4);
    int*   cursor  = (int*)alloc((size_t)NN * 4);
    int*   col     = (int*)alloc((size_t)(EE + NN) * 4);
    int*   bsums   = (int*)alloc((size_t)((NB_SCAN + 63) & ~63) * 4);

    hipMemsetAsync(deg, 0, (size_t)NN * 4, stream);
    hipMemsetAsync(cursor, 0, (size_t)NN * 4, stream);

    int eb = (EE + NN + 255) / 256;
    k_count  <<<eb, 256, 0, stream>>>(ei, deg);
    k_scan1  <<<NB_SCAN, 256, 0, stream>>>(deg, offs, bsums);
    k_scan2  <<<1, 512, 0, stream>>>(bsums);
    k_scan3  <<<NB_SCAN, 256, 0, stream>>>(offs, bsums);
    k_scatter<<<eb, 256, 0, stream>>>(ei, offs, cursor, col);
    k_out_init<<<(GG + 255) / 256, 256, 0, stream>>>(hb, out);

    const float* cur_in = x;
    int fin = 128;
    for (int L = 0; L < 3; L++) {
        k_gemm<<<NN / 16, 256, 0, stream>>>(
            cur_in, Wm[L], As[L], Ad[L], Hh, als, ald, fin);
        k_agg <<<NN / 16, 256, 0, stream>>>(
            Hh, als, ald, offs, deg, col, Bb[L], Bf, batch, hw, out, (L == 2) ? 1 : 0);
        cur_in = Bf;
        fin = 64;
    }
}

// Round 9
// 540.508 us; speedup vs baseline: 1.5486x; 1.1990x over previous
//
#include <hip/hip_runtime.h>
#include <hip/hip_bf16.h>
#include <hip/hip_fp16.h>
#include <cstdint>
#include <cstddef>

#define NN 100000
#define EE 1600000
#define GG 2048

constexpr int NB_SCAN = (NN + 255) / 256; // 391 blocks over nodes

__device__ __forceinline__ float lrelu(float v) { return v > 0.f ? v : 0.2f * v; }

// ---------------- CSR build (dst -> list of src), reused by all 3 layers ----
// rank[i] = arrival order of edge i at its dst -> scatter needs no atomics.
__global__ void k_count(const int* __restrict__ ei, int* __restrict__ deg,
                        int* __restrict__ rank) {
    int i = blockIdx.x * blockDim.x + threadIdx.x;
    if (i >= EE + NN) return;
    int d = (i < EE) ? ei[EE + i] : (i - EE);
    rank[i] = atomicAdd(&deg[d], 1);
}

__global__ void k_scan1(const int* __restrict__ deg, int* __restrict__ offs,
                        int* __restrict__ bsums) {
    __shared__ int tmp[256];
    int tid = threadIdx.x;
    int i = blockIdx.x * 256 + tid;
    int v = (i < NN) ? deg[i] : 0;
    tmp[tid] = v; __syncthreads();
    for (int off = 1; off < 256; off <<= 1) {
        int t = (tid >= off) ? tmp[tid - off] : 0;
        __syncthreads();
        tmp[tid] += t;
        __syncthreads();
    }
    if (i < NN) offs[i] = tmp[tid] - v;   // exclusive within block
    if (tid == 255) bsums[blockIdx.x] = tmp[255];
}

__global__ void k_scan2(int* __restrict__ bsums) {
    __shared__ int tmp[512];
    int tid = threadIdx.x;
    int v = (tid < NB_SCAN) ? bsums[tid] : 0;
    tmp[tid] = v; __syncthreads();
    for (int off = 1; off < 512; off <<= 1) {
        int t = (tid >= off) ? tmp[tid - off] : 0;
        __syncthreads();
        tmp[tid] += t;
        __syncthreads();
    }
    if (tid < NB_SCAN) bsums[tid] = tmp[tid] - v;  // exclusive block offsets
}

__global__ void k_scan3(int* __restrict__ offs, const int* __restrict__ bsums) {
    int i = blockIdx.x * 256 + threadIdx.x;
    if (i < NN) offs[i] += bsums[blockIdx.x];
}

__global__ void k_scatter(const int* __restrict__ ei, const int* __restrict__ offs,
                          const int* __restrict__ rank, int* __restrict__ col) {
    int i = blockIdx.x * blockDim.x + threadIdx.x;
    if (i >= EE + NN) return;
    int s, d;
    if (i < EE) { s = ei[i]; d = ei[EE + i]; } else { s = d = i - EE; }
    col[offs[d] + rank[i]] = s;
}

// ---------------- GEMM + fused attention-logit epilogue ---------------------
// One wave = 4 rows. x-row pointers are wave-uniform (forced to SGPR via
// readfirstlane) -> x reads issue on the SMEM pipe, leaving LDS idle and the
// VALU free for FMAs. W reads are lane-consecutive (L2-resident, 32 KB max).
template <int FIN>
__global__ __launch_bounds__(256) void k_gemm(const float* __restrict__ X,
                                              const float* __restrict__ W,
                                              const float* __restrict__ asrc,
                                              const float* __restrict__ adst,
                                              float* __restrict__ H,
                                              float* __restrict__ als,
                                              float* __restrict__ ald) {
    int j  = threadIdx.x & 63;   // output col
    int ty = threadIdx.x >> 6;   // wave id 0..3
    int row = __builtin_amdgcn_readfirstlane(blockIdx.x * 16 + ty * 4);
    const float* x0 = X + (size_t)row * FIN;
    const float* x1 = x0 + FIN;
    const float* x2 = x1 + FIN;
    const float* x3 = x2 + FIN;
    float a0 = 0.f, a1 = 0.f, a2 = 0.f, a3 = 0.f;
#pragma unroll
    for (int k = 0; k < FIN; k += 4) {
        float4 xa = *(const float4*)(x0 + k);
        float4 xb = *(const float4*)(x1 + k);
        float4 xc = *(const float4*)(x2 + k);
        float4 xd = *(const float4*)(x3 + k);
        float w0 = W[(k + 0) * 64 + j];
        float w1 = W[(k + 1) * 64 + j];
        float w2 = W[(k + 2) * 64 + j];
        float w3 = W[(k + 3) * 64 + j];
        a0 += xa.x * w0 + xa.y * w1 + xa.z * w2 + xa.w * w3;
        a1 += xb.x * w0 + xb.y * w1 + xb.z * w2 + xb.w * w3;
        a2 += xc.x * w0 + xc.y * w1 + xc.z * w2 + xc.w * w3;
        a3 += xd.x * w0 + xd.y * w1 + xd.z * w2 + xd.w * w3;
    }
    H[(size_t)(row + 0) * 64 + j] = a0;
    H[(size_t)(row + 1) * 64 + j] = a1;
    H[(size_t)(row + 2) * 64 + j] = a2;
    H[(size_t)(row + 3) * 64 + j] = a3;
    float asj = asrc[j], adj = adst[j];
    float accs[4] = {a0, a1, a2, a3};
#pragma unroll
    for (int r = 0; r < 4; r++) {
        float vs = accs[r] * asj;
        float vd = accs[r] * adj;
#pragma unroll
        for (int off = 8; off > 0; off >>= 1) {
            vs += __shfl_xor(vs, off, 64);
            vd += __shfl_xor(vd, off, 64);
        }
        if ((j & 15) == 0) {
            int h = j >> 4;
            als[(size_t)(row + r) * 4 + h] = vs;
            ald[(size_t)(row + r) * 4 + h] = vd;
        }
    }
}

// 16 lanes per node: softmax over edges + fp32 row gather, no cross-lane combine.
// Block = 256 threads = 16 nodes. Staging is written UNCONDITIONALLY (zeros for
// e >= len) and handed off through a block-uniform __syncthreads().
// fp32 messages: error vs reference ~1e-6 on every edge-order realization
// (fp16 was marginal: 0.004-0.023 across realizations vs 0.0146 threshold).
#define LWPITCH 260   // 64*4 + 4 pad words
__global__ __launch_bounds__(256) void k_agg(
    const float* __restrict__ H, const float* __restrict__ als,
    const float* __restrict__ ald, const int* __restrict__ offs,
    const int* __restrict__ deg, const int* __restrict__ col,
    const float* __restrict__ bias, float* __restrict__ Hout,
    const int* __restrict__ batch, const float* __restrict__ hw,
    float* __restrict__ out, int last) {
    __shared__ float lws[16 * LWPITCH];  // [group][edge*4 + head]
    __shared__ int   lsi[16][64];        // [group][edge] = src index
    int tid = threadIdx.x;
    int g = tid >> 4;          // group (node) 0..15
    int l = tid & 15;          // lane in group = float4-chunk index 0..15
    int n = blockIdx.x * 16 + g;   // NN % 16 == 0 -> always valid
    int start = offs[n];
    int len = deg[n];
    float4 ad4 = ((const float4*)ald)[n];
    int hsel = l >> 2;         // head of this lane's channel quad
    const float4* Hp = (const float4*)H + l;
    float* lw = lws + g * LWPITCH;
    bool fast = (len <= 64);
    float inv = 1.f;

    if (fast) {
        // ---- stage: lane e (of 16) owns edges e, e+16, e+32, e+48 ----
        float ev[4][4];
        int   si[4];
        bool  vld[4];
        float m0 = -1e30f, m1 = -1e30f, m2 = -1e30f, m3 = -1e30f;
#pragma unroll
        for (int it = 0; it < 4; it++) {
            int e = l + it * 16;
            vld[it] = (e < len);
            int s = vld[it] ? col[start + e] : 0;
            si[it] = s;
            float4 a = ((const float4*)als)[s];
            ev[it][0] = lrelu(a.x + ad4.x); ev[it][1] = lrelu(a.y + ad4.y);
            ev[it][2] = lrelu(a.z + ad4.z); ev[it][3] = lrelu(a.w + ad4.w);
            if (vld[it]) {
                m0 = fmaxf(m0, ev[it][0]); m1 = fmaxf(m1, ev[it][1]);
                m2 = fmaxf(m2, ev[it][2]); m3 = fmaxf(m3, ev[it][3]);
            }
        }
#pragma unroll
        for (int off = 8; off > 0; off >>= 1) {
            m0 = fmaxf(m0, __shfl_xor(m0, off, 16));
            m1 = fmaxf(m1, __shfl_xor(m1, off, 16));
            m2 = fmaxf(m2, __shfl_xor(m2, off, 16));
            m3 = fmaxf(m3, __shfl_xor(m3, off, 16));
        }
        float s0 = 0.f, s1 = 0.f, s2 = 0.f, s3 = 0.f;
#pragma unroll
        for (int it = 0; it < 4; it++) {
            int e = l + it * 16;
            float w0 = vld[it] ? __expf(ev[it][0] - m0) : 0.f;
            float w1 = vld[it] ? __expf(ev[it][1] - m1) : 0.f;
            float w2 = vld[it] ? __expf(ev[it][2] - m2) : 0.f;
            float w3 = vld[it] ? __expf(ev[it][3] - m3) : 0.f;
            s0 += w0; s1 += w1; s2 += w2; s3 += w3;
            ((float4*)(lw + e * 4))[0] = make_float4(w0, w1, w2, w3);  // unconditional
            lsi[g][e] = vld[it] ? si[it] : 0;                          // unconditional
        }
#pragma unroll
        for (int off = 8; off > 0; off >>= 1) {
            s0 += __shfl_xor(s0, off, 16); s1 += __shfl_xor(s1, off, 16);
            s2 += __shfl_xor(s2, off, 16); s3 += __shfl_xor(s3, off, 16);
        }
        float smh = hsel == 0 ? s0 : hsel == 1 ? s1 : hsel == 2 ? s2 : s3;
        inv = 1.f / (smh + 1e-16f);
    }

    __syncthreads();   // block-uniform handoff: staging -> gather

    float4 acc = {0.f, 0.f, 0.f, 0.f};
    if (fast) {
        // ---- gather: lane l fetches float4 chunk l of each src row ----
        int e = 0;
        for (; e + 4 <= len; e += 4) {   // 4 independent rows in flight per group
            int sa = lsi[g][e], sb = lsi[g][e + 1], sc = lsi[g][e + 2], sd = lsi[g][e + 3];
            float wa = lw[(e + 0) * 4 + hsel];
            float wb = lw[(e + 1) * 4 + hsel];
            float wc = lw[(e + 2) * 4 + hsel];
            float wd = lw[(e + 3) * 4 + hsel];
            float4 ha = Hp[(size_t)sa * 16];
            float4 hb = Hp[(size_t)sb * 16];
            float4 hc = Hp[(size_t)sc * 16];
            float4 hd = Hp[(size_t)sd * 16];
            acc.x += wa * ha.x + wb * hb.x + wc * hc.x + wd * hd.x;
            acc.y += wa * ha.y + wb * hb.y + wc * hc.y + wd * hd.y;
            acc.z += wa * ha.z + wb * hb.z + wc * hc.z + wd * hd.z;
            acc.w += wa * ha.w + wb * hb.w + wc * hc.w + wd * hd.w;
        }
        for (; e < len; e++) {
            int sa = lsi[g][e];
            float wa = lw[e * 4 + hsel];
            float4 ha = Hp[(size_t)sa * 16];
            acc.x += wa * ha.x; acc.y += wa * ha.y;
            acc.z += wa * ha.z; acc.w += wa * ha.w;
        }
    } else {
        // vanishingly-rare fallback (deg > 64): 3-phase recompute, no LDS
        float m0 = -1e30f, m1 = -1e30f, m2 = -1e30f, m3 = -1e30f;
        for (int e = l; e < len; e += 16) {
            int s = col[start + e];
            float4 a = ((const float4*)als)[s];
            m0 = fmaxf(m0, lrelu(a.x + ad4.x)); m1 = fmaxf(m1, lrelu(a.y + ad4.y));
            m2 = fmaxf(m2, lrelu(a.z + ad4.z)); m3 = fmaxf(m3, lrelu(a.w + ad4.w));
        }
#pragma unroll
        for (int off = 8; off > 0; off >>= 1) {
            m0 = fmaxf(m0, __shfl_xor(m0, off, 16));
            m1 = fmaxf(m1, __shfl_xor(m1, off, 16));
            m2 = fmaxf(m2, __shfl_xor(m2, off, 16));
            m3 = fmaxf(m3, __shfl_xor(m3, off, 16));
        }
        float s0 = 0.f, s1 = 0.f, s2 = 0.f, s3 = 0.f;
        for (int e = l; e < len; e += 16) {
            int s = col[start + e];
            float4 a = ((const float4*)als)[s];
            s0 += __expf(lrelu(a.x + ad4.x) - m0); s1 += __expf(lrelu(a.y + ad4.y) - m1);
            s2 += __expf(lrelu(a.z + ad4.z) - m2); s3 += __expf(lrelu(a.w + ad4.w) - m3);
        }
#pragma unroll
        for (int off = 8; off > 0; off >>= 1) {
            s0 += __shfl_xor(s0, off, 16); s1 += __shfl_xor(s1, off, 16);
            s2 += __shfl_xor(s2, off, 16); s3 += __shfl_xor(s3, off, 16);
        }
        float mh = hsel == 0 ? m0 : hsel == 1 ? m1 : hsel == 2 ? m2 : m3;
        float sh = hsel == 0 ? s0 : hsel == 1 ? s1 : hsel == 2 ? s2 : s3;
        float ih = 1.f / (sh + 1e-16f);
        float ah = hsel == 0 ? ad4.x : hsel == 1 ? ad4.y : hsel == 2 ? ad4.z : ad4.w;
        for (int e = 0; e < len; e++) {
            int s = col[start + e];
            float alpha = __expf(lrelu(als[(size_t)s * 4 + hsel] + ah) - mh) * ih;
            float4 ha = Hp[(size_t)s * 16];
            acc.x += alpha * ha.x; acc.y += alpha * ha.y;
            acc.z += alpha * ha.z; acc.w += alpha * ha.w;
        }
        inv = 1.f;
    }

    float4 b4 = ((const float4*)bias)[l];
    float4 o4;
    o4.x = fmaxf(acc.x * inv + b4.x, 0.f);
    o4.y = fmaxf(acc.y * inv + b4.y, 0.f);
    o4.z = fmaxf(acc.z * inv + b4.z, 0.f);
    o4.w = fmaxf(acc.w * inv + b4.w, 0.f);
    if (!last) {
        ((float4*)Hout)[(size_t)n * 16 + l] = o4;
    } else {
        float4 w4 = ((const float4*)hw)[l];
        float t = o4.x * w4.x + o4.y * w4.y + o4.z * w4.z + o4.w * w4.w;
#pragma unroll
        for (int off = 8; off > 0; off >>= 1) t += __shfl_xor(t, off, 16);
        if (l == 0) atomicAdd(&out[batch[n]], t);
    }
}

// ---------------- output init ------------------------------------------------
__global__ void k_out_init(const float* __restrict__ head_b, float* __restrict__ out) {
    int g = blockIdx.x * blockDim.x + threadIdx.x;
    if (g < GG) out[g] = head_b[0];
}

// ---------------- launch -----------------------------------------------------
extern "C" void kernel_launch(void* const* d_in, const int* in_sizes, int n_in,
                              void* d_out, int out_size, void* d_ws, size_t ws_size,
                              hipStream_t stream) {
    const float* x     = (const float*)d_in[0];
    const int*   ei    = (const int*)d_in[1];
    const int*   batch = (const int*)d_in[2];
    const float* Wm[3] = {(const float*)d_in[3], (const float*)d_in[7],  (const float*)d_in[11]};
    const float* As[3] = {(const float*)d_in[4], (const float*)d_in[8],  (const float*)d_in[12]};
    const float* Ad[3] = {(const float*)d_in[5], (const float*)d_in[9],  (const float*)d_in[13]};
    const float* Bb[3] = {(const float*)d_in[6], (const float*)d_in[10], (const float*)d_in[14]};
    const float* hw = (const float*)d_in[15];
    const float* hb = (const float*)d_in[16];
    float* out = (float*)d_out;

    uint8_t* w = (uint8_t*)d_ws;
    auto alloc = [&](size_t bytes) -> void* {
        void* p = (void*)w;
        w += (bytes + 255) & ~(size_t)255;
        return p;
    };
    float* H       = (float*)alloc((size_t)NN * 64 * 4);     // fp32 gather rows
    float* Bf      = (float*)alloc((size_t)NN * 64 * 4);     // aggregated output
    float* als     = (float*)alloc((size_t)NN * 4 * 4);
    float* ald     = (float*)alloc((size_t)NN * 4 * 4);
    int*   deg     = (int*)alloc((size_t)NN * 4);
    int*   offs    = (int*)alloc((size_t)NN * 4);
    int*   rank    = (int*)alloc((size_t)(EE + NN) * 4);
    int*   col     = (int*)alloc((size_t)(EE + NN) * 4);
    int*   bsums   = (int*)alloc((size_t)((NB_SCAN + 63) & ~63) * 4);

    hipMemsetAsync(deg, 0, (size_t)NN * 4, stream);

    int eb = (EE + NN + 255) / 256;
    k_count  <<<eb, 256, 0, stream>>>(ei, deg, rank);
    k_scan1  <<<NB_SCAN, 256, 0, stream>>>(deg, offs, bsums);
    k_scan2  <<<1, 512, 0, stream>>>(bsums);
    k_scan3  <<<NB_SCAN, 256, 0, stream>>>(offs, bsums);
    k_scatter<<<eb, 256, 0, stream>>>(ei, offs, rank, col);
    k_out_init<<<(GG + 255) / 256, 256, 0, stream>>>(hb, out);

    const float* cur_in = x;
    for (int L = 0; L < 3; L++) {
        if (L == 0)
            k_gemm<128><<<NN / 16, 256, 0, stream>>>(
                cur_in, Wm[L], As[L], Ad[L], H, als, ald);
        else
            k_gemm<64><<<NN / 16, 256, 0, stream>>>(
                cur_in, Wm[L], As[L], Ad[L], H, als, ald);
        k_agg <<<NN / 16, 256, 0, stream>>>(
            H, als, ald, offs, deg, col, Bb[L], Bf, batch, hw, out, (L == 2) ? 1 : 0);
        cur_in = Bf;
    }
}